// Round 12
// baseline (120.087 us; speedup 1.0000x reference)
//
#include <hip/hip_runtime.h>

#define Bn 4
#define Sn 2048
#define Dn 768
#define Hn 12
#define DKn 64
#define Mn (Bn * Sn)

typedef __bf16 bf16x8 __attribute__((ext_vector_type(8)));
typedef float f32x4 __attribute__((ext_vector_type(4)));

static __device__ __forceinline__ float4 ld4(const float* p) { return *(const float4*)p; }

static __device__ __forceinline__ f32x4 mfma16(bf16x8 a, bf16x8 b, f32x4 c) {
  return __builtin_amdgcn_mfma_f32_16x16x32_bf16(a, b, c, 0, 0, 0);
}

// global -> LDS direct copy, 16B per lane. LDS dest = wave-uniform base + lane*16.
static __device__ __forceinline__ void glds16(const void* g, void* l) {
  __builtin_amdgcn_global_load_lds(
      (const __attribute__((address_space(1))) unsigned int*)(uintptr_t)g,
      (__attribute__((address_space(3))) unsigned int*)(unsigned int)(uintptr_t)l, 16, 0, 0);
}

// Swizzled 16B fragment read from a [rows][64 bf16] tile (128B row stride).
// Content at swizzled chunk x of row r = original chunk x ^ (r&7).
static __device__ __forceinline__ bf16x8 ldsfrag(const __bf16* base, int row, int kbyte) {
  const char* p = (const char*)base + row * 128 + (kbyte ^ ((row & 7) << 4));
  return *(const bf16x8*)p;
}

static __device__ __forceinline__ void lds_w16(__bf16* base, int row, int col, __bf16 v) {
  char* p = (char*)base + row * 128 + ((col * 2) ^ ((row & 7) << 4));
  *(__bf16*)p = v;
}

static __device__ __forceinline__ bf16x8 cvt8(float4 a, float4 b) {
  bf16x8 o;
  o[0] = (__bf16)a.x; o[1] = (__bf16)a.y; o[2] = (__bf16)a.z; o[3] = (__bf16)a.w;
  o[4] = (__bf16)b.x; o[5] = (__bf16)b.y; o[6] = (__bf16)b.z; o[7] = (__bf16)b.w;
  return o;
}

// ---------------------------------------------------------------------------
// prep kernel (launch 1), grid (148), block 256:
//  blocks 0..143 -> W transpose, 128x128 f32 tile each (4 x 64x64 subtiles)
//  blocks 144..147 -> per-batch mask compaction index
// ---------------------------------------------------------------------------
__global__ __launch_bounds__(256) void prep_kernel(
    const unsigned char* __restrict__ mask,
    const float* __restrict__ Wq, const float* __restrict__ Wk,
    const float* __restrict__ Wv, const float* __restrict__ Wo,
    __bf16* __restrict__ Wt, int* __restrict__ cidx, int* __restrict__ nbp) {
  const int t = threadIdx.x;
  const int bid = blockIdx.x;

  if (bid < 144) {
    __shared__ __bf16 T[64][72];
    const int zi = bid / 36;
    const int rem = bid % 36;
    const int bx = rem % 6, by = rem / 6;
    const float* W = zi == 0 ? Wq : zi == 1 ? Wk : zi == 2 ? Wv : Wo;
    __bf16* out = Wt + (size_t)zi * Dn * Dn;
    const int k0 = bx * 128, n0 = by * 128;
#pragma unroll
    for (int sk = 0; sk < 2; ++sk)
#pragma unroll
      for (int sn = 0; sn < 2; ++sn) {
        const int kk0 = k0 + sk * 64, nn0 = n0 + sn * 64;
        __syncthreads();
#pragma unroll
        for (int i = 0; i < 4; ++i) {
          int flat = t + i * 256;
          int row = flat >> 4;
          int c4 = (flat & 15) * 4;
          float4 vv = ld4(&W[(size_t)(kk0 + row) * Dn + nn0 + c4]);
          T[c4 + 0][row] = (__bf16)vv.x;
          T[c4 + 1][row] = (__bf16)vv.y;
          T[c4 + 2][row] = (__bf16)vv.z;
          T[c4 + 3][row] = (__bf16)vv.w;
        }
        __syncthreads();
#pragma unroll
        for (int i = 0; i < 2; ++i) {
          int flat = t + i * 256;
          int row = flat >> 3;
          int c8 = (flat & 7) * 8;
          *(bf16x8*)&out[(size_t)(nn0 + row) * Dn + kk0 + c8] = *(bf16x8*)&T[row][c8];
        }
      }
    return;
  }

  // mask index build, one block per batch
  __shared__ int dcnt;
  __shared__ int cnts[256];
  __shared__ int offs[256];
  const int b = bid - 144;
  if (t == 0) dcnt = 0;
  __syncthreads();
  int c = 0;
#pragma unroll
  for (int i = 0; i < 32; ++i) c += (mask[t * 32 + i] != 0) ? 1 : 0;
  atomicAdd(&dcnt, c);
  __syncthreads();
  const int mflag = dcnt > 2457;  // >30% of first 8192 bytes nonzero => byte-bool
  const unsigned char* m8 = mask + (size_t)b * Sn;
  const int* m32 = (const int*)mask + (size_t)b * Sn;
  bool um[8];
  int lc = 0;
#pragma unroll
  for (int i = 0; i < 8; ++i) {
    const int s = t * 8 + i;
    const bool masked = mflag ? (m8[s] != 0) : (m32[s] != 0);
    um[i] = !masked;
    lc += um[i] ? 1 : 0;
  }
  cnts[t] = lc;
  __syncthreads();
  if (t == 0) {
    int acc = 0;
    for (int i = 0; i < 256; ++i) {
      offs[i] = acc;
      acc += cnts[i];
    }
    nbp[b] = acc;
  }
  __syncthreads();
  int o = offs[t];
  int* out = cidx + (size_t)b * Sn;
#pragma unroll
  for (int i = 0; i < 8; ++i)
    if (um[i]) out[o++] = t * 8 + i;
}

// ---------------------------------------------------------------------------
// convert kernel (launch 2), grid (4096, 1, 3), block 256:
//  z=0: q f32->bf16 (blocks 0..3071, 2048 elems each)
//  z=1: k gather-compact-convert (2 rows/block, threads 0..191)
//  z=2: v gather-compact-convert
// ---------------------------------------------------------------------------
__global__ __launch_bounds__(256) void convert_kernel(
    const float* __restrict__ q, const float* __restrict__ k, const float* __restrict__ v,
    const int* __restrict__ cidx, const int* __restrict__ nbp,
    __bf16* __restrict__ qb, __bf16* __restrict__ kb, __bf16* __restrict__ vb) {
  const int t = threadIdx.x;
  const int z = blockIdx.z;
  const int bid = blockIdx.x;

  if (z == 0) {
    if (bid >= 3072) return;
    size_t i = ((size_t)bid * 256 + t) * 8;
    *(bf16x8*)(qb + i) = cvt8(ld4(q + i), ld4(q + i + 4));
    return;
  }
  if (t >= 192) return;
  const float* src = z == 1 ? k : v;
  __bf16* dst = z == 1 ? kb : vb;
  const int b = bid >> 10;
  const int i = ((bid & 1023) << 1) + (t / 96);
  const int c8 = (t % 96) * 8;
  const int nb = nbp[b];
  __bf16* orow = dst + ((size_t)b * Sn + i) * Dn + c8;
  if (i < nb) {
    const int s = cidx[b * Sn + i];
    const float* irow = src + ((size_t)b * Sn + s) * Dn + c8;
    *(bf16x8*)orow = cvt8(ld4(irow), ld4(irow + 4));
  } else {
    bf16x8 zz = {};
    *(bf16x8*)orow = zz;
  }
}

// ---------------------------------------------------------------------------
// MFMA GEMM core (round-5 proven): both operands via glds16. 128x128, BK=64.
// MODE 0: bf16 head-split [b][h][s][dk].  MODE 1: f32 [m][768].
// MODE 2: bf16 head-split transposed [b][h][dk][s]  (for V).
template <int MODE>
static __device__ __forceinline__ void gemm_mfma_core(__bf16* __restrict__ As,
                                                      __bf16* __restrict__ Bs,
                                                      const __bf16* __restrict__ X,
                                                      const __bf16* __restrict__ Bt,
                                                      const float* __restrict__ bias,
                                                      void* __restrict__ Y) {
  const int tid = threadIdx.x;
  const int lane = tid & 63;
  const int wave = __builtin_amdgcn_readfirstlane(tid >> 6);
  const int l15 = lane & 15, lq = lane >> 4;
  const int m0 = blockIdx.x * 128, n0 = blockIdx.y * 128;
  const int wr = wave >> 1, wc = wave & 1;

  f32x4 acc[4][4];
#pragma unroll
  for (int i = 0; i < 4; ++i)
#pragma unroll
    for (int j = 0; j < 4; ++j) acc[i][j] = (f32x4){0.f, 0.f, 0.f, 0.f};

  for (int kt = 0; kt < Dn / 64; ++kt) {
    __syncthreads();
#pragma unroll
    for (int i = 0; i < 4; ++i) {
      int r0 = (i * 4 + wave) * 8;
      int row = r0 + (lane >> 3);
      int chunk = (lane & 7) ^ (row & 7);
      glds16(X + (size_t)(m0 + row) * Dn + kt * 64 + chunk * 8, As + r0 * 64);
      glds16(Bt + (size_t)(n0 + row) * Dn + kt * 64 + chunk * 8, Bs + r0 * 64);
    }
    __syncthreads();
#pragma unroll
    for (int kk = 0; kk < 2; ++kk) {
      bf16x8 a[4], b[4];
#pragma unroll
      for (int i = 0; i < 4; ++i) a[i] = ldsfrag(As, wr * 64 + i * 16 + l15, kk * 64 + lq * 16);
#pragma unroll
      for (int j = 0; j < 4; ++j) b[j] = ldsfrag(Bs, wc * 64 + j * 16 + l15, kk * 64 + lq * 16);
#pragma unroll
      for (int i = 0; i < 4; ++i)
#pragma unroll
        for (int j = 0; j < 4; ++j) acc[i][j] = mfma16(a[i], b[j], acc[i][j]);
    }
  }

#pragma unroll
  for (int i = 0; i < 4; ++i)
#pragma unroll
    for (int j = 0; j < 4; ++j) {
      const int gcol = n0 + wc * 64 + j * 16 + l15;
      const float bv = bias[gcol];
#pragma unroll
      for (int r = 0; r < 4; ++r) {
        const int grow = m0 + wr * 64 + i * 16 + lq * 4 + r;
        const float val = acc[i][j][r] + bv;
        if (MODE == 0) {
          const int b = grow >> 11, s = grow & (Sn - 1);
          const int h = gcol >> 6, dk = gcol & 63;
          ((__bf16*)Y)[(((size_t)b * Hn + h) * Sn + s) * DKn + dk] = (__bf16)val;
        } else if (MODE == 2) {
          const int b = grow >> 11, s = grow & (Sn - 1);
          const int h = gcol >> 6, dk = gcol & 63;
          ((__bf16*)Y)[(((size_t)b * Hn + h) * DKn + dk) * Sn + s] = (__bf16)val;
        } else {
          ((float*)Y)[(size_t)grow * Dn + gcol] = val;
        }
      }
    }
}

__global__ __launch_bounds__(256, 4) void qkv_gemm_mfma_kernel(
    const __bf16* __restrict__ qb, const __bf16* __restrict__ kb, const __bf16* __restrict__ vb,
    const __bf16* __restrict__ Wt, const int* __restrict__ nbp,
    const float* __restrict__ bq, const float* __restrict__ bk, const float* __restrict__ bv,
    __bf16* __restrict__ qh, __bf16* __restrict__ kh, __bf16* __restrict__ vht) {
  __shared__ __bf16 As[128 * 64];
  __shared__ __bf16 Bs[128 * 64];
  const int z = blockIdx.z;
  if (z != 0) {
    // compacted K/V rows: skip tiles fully beyond this batch's live rows
    const int m0 = blockIdx.x * 128;
    const int b = m0 >> 11, ml = m0 & (Sn - 1);
    const int lim = (nbp[b] + 127) & ~127;
    if (ml >= lim) return;
  }
  if (z == 0) {
    gemm_mfma_core<0>(As, Bs, qb, Wt, bq, qh);
  } else if (z == 1) {
    gemm_mfma_core<0>(As, Bs, kb, Wt + (size_t)Dn * Dn, bk, kh);
  } else {
    gemm_mfma_core<2>(As, Bs, vb, Wt + 2 * (size_t)Dn * Dn, bv, vht);
  }
}

__global__ __launch_bounds__(256, 4) void out_gemm_mfma_kernel(const __bf16* __restrict__ ctxb,
                                                               const __bf16* __restrict__ Wot,
                                                               const float* __restrict__ bo,
                                                               float* __restrict__ out) {
  __shared__ __bf16 As[128 * 64];
  __shared__ __bf16 Bs[128 * 64];
  gemm_mfma_core<1>(As, Bs, ctxb, Wot, bo, out);
}

// ---------------------------------------------------------------------------
// Flash attention over COMPACTED keys, fixed-M softmax (round-5 structure).
// Grid: 768 linear blocks, XCD-swizzled so the 16 q-tile blocks of one (b,h)
// land on ONE XCD (shared K/V becomes L2-local). 4 waves x 32 q-rows.
// s_setprio(1) around MFMA clusters (T5).
__global__ __launch_bounds__(256, 3) void attn_mfma_kernel(
    const __bf16* __restrict__ qh, const __bf16* __restrict__ kh, const __bf16* __restrict__ vht,
    const int* __restrict__ nbp, __bf16* __restrict__ ctxb) {
  __shared__ __bf16 QPs[128 * 64];    // Q at start, then P (wave-private rows)
  __shared__ __bf16 KVs[4][64 * 64];  // K0 K1 V0 V1
  const int tid = threadIdx.x;
  const int lane = tid & 63;
  const int wave = __builtin_amdgcn_readfirstlane(tid >> 6);
  const int l15 = lane & 15, lq = lane >> 4;
  // XCD-aware swizzle: hw block d -> logical l; 768 = 8 XCDs * 96.
  const int d = blockIdx.x;
  const int l = (d & 7) * 96 + (d >> 3);
  const int q0 = (l & 15) * 128;
  const int bh = l >> 4;
  const int b = bh / Hn, h = bh % Hn;
  const int nb = nbp[b];
  const int NT = (nb + 63) >> 6;
  const __bf16* Qg = qh + (size_t)bh * Sn * DKn;
  const __bf16* Kg = kh + (size_t)bh * Sn * DKn;
  const __bf16* Vg = vht + (size_t)bh * DKn * Sn;
  const float C1 = 0.18033688011112042f;  // log2(e)/8
  const float C2 = -23.083120654223414f;  // -16*log2(e)

  auto stageKV = [&](int t, int buf) {
#pragma unroll
    for (int i = 0; i < 2; ++i) {
      int r0 = wave * 16 + i * 8;
      int row = r0 + (lane >> 3);
      int chunk = (lane & 7) ^ (row & 7);
      glds16(Kg + (size_t)(t * 64 + row) * DKn + chunk * 8, (__bf16*)KVs[buf] + r0 * 64);
      glds16(Vg + (size_t)row * Sn + t * 64 + chunk * 8, (__bf16*)KVs[2 + buf] + r0 * 64);
    }
  };

  // stage Q rows [wave*32, wave*32+32)
#pragma unroll
  for (int i = 0; i < 4; ++i) {
    int r0 = wave * 32 + i * 8;
    int row = r0 + (lane >> 3);
    int chunk = (lane & 7) ^ (row & 7);
    glds16(Qg + (size_t)(q0 + row) * DKn + chunk * 8, (__bf16*)QPs + r0 * 64);
  }
  stageKV(0, 0);
  __syncthreads();

  bf16x8 aq[2][2];
#pragma unroll
  for (int qb = 0; qb < 2; ++qb)
#pragma unroll
    for (int kk = 0; kk < 2; ++kk)
      aq[qb][kk] = ldsfrag(QPs, wave * 32 + qb * 16 + l15, kk * 64 + lq * 16);

  f32x4 ctx[2][4];
  float lsum[2][4];
#pragma unroll
  for (int qb = 0; qb < 2; ++qb)
#pragma unroll
    for (int j = 0; j < 4; ++j) {
      ctx[qb][j] = (f32x4){0.f, 0.f, 0.f, 0.f};
      lsum[qb][j] = 0.f;
    }

  int cur = 0;
  for (int t = 0; t < NT; ++t) {
    if (t + 1 < NT) stageKV(t + 1, cur ^ 1);

    // QK^T
    f32x4 sc[2][4];
#pragma unroll
    for (int qb = 0; qb < 2; ++qb)
#pragma unroll
      for (int j = 0; j < 4; ++j) sc[qb][j] = (f32x4){0.f, 0.f, 0.f, 0.f};
    __builtin_amdgcn_s_setprio(1);
#pragma unroll
    for (int kk = 0; kk < 2; ++kk)
#pragma unroll
      for (int j = 0; j < 4; ++j) {
        bf16x8 bk = ldsfrag(KVs[cur], j * 16 + l15, kk * 64 + lq * 16);
        sc[0][j] = mfma16(aq[0][kk], bk, sc[0][j]);
        sc[1][j] = mfma16(aq[1][kk], bk, sc[1][j]);
      }
    __builtin_amdgcn_s_setprio(0);

    // softmax (fixed M) + P -> LDS (wave-private rows)
    if (t != NT - 1) {
#pragma unroll
      for (int qb = 0; qb < 2; ++qb)
#pragma unroll
        for (int j = 0; j < 4; ++j)
#pragma unroll
          for (int r = 0; r < 4; ++r) {
            const float p = __builtin_amdgcn_exp2f(fmaf(sc[qb][j][r], C1, C2));
            lsum[qb][r] += p;
            lds_w16(QPs, wave * 32 + qb * 16 + lq * 4 + r, j * 16 + l15, (__bf16)p);
          }
    } else {
      const int limit = nb - t * 64;
      bool live[4];
#pragma unroll
      for (int j = 0; j < 4; ++j) live[j] = (j * 16 + l15) < limit;
#pragma unroll
      for (int qb = 0; qb < 2; ++qb)
#pragma unroll
        for (int j = 0; j < 4; ++j)
#pragma unroll
          for (int r = 0; r < 4; ++r) {
            float p = __builtin_amdgcn_exp2f(fmaf(sc[qb][j][r], C1, C2));
            p = live[j] ? p : 0.f;
            lsum[qb][r] += p;
            lds_w16(QPs, wave * 32 + qb * 16 + lq * 4 + r, j * 16 + l15, (__bf16)p);
          }
    }

    // PV
    bf16x8 pa[2][2];
#pragma unroll
    for (int qb = 0; qb < 2; ++qb)
#pragma unroll
      for (int kk = 0; kk < 2; ++kk)
        pa[qb][kk] = ldsfrag(QPs, wave * 32 + qb * 16 + l15, kk * 64 + lq * 16);
    __builtin_amdgcn_s_setprio(1);
#pragma unroll
    for (int kk = 0; kk < 2; ++kk)
#pragma unroll
      for (int j = 0; j < 4; ++j) {
        bf16x8 bv = ldsfrag(KVs[2 + cur], j * 16 + l15, kk * 64 + lq * 16);
        ctx[0][j] = mfma16(pa[0][kk], bv, ctx[0][j]);
        ctx[1][j] = mfma16(pa[1][kk], bv, ctx[1][j]);
      }
    __builtin_amdgcn_s_setprio(0);

    __syncthreads();
    cur ^= 1;
  }

  // one reduction tree for l over the 16 col-lanes
#pragma unroll
  for (int sh = 1; sh <= 8; sh <<= 1)
#pragma unroll
    for (int qb = 0; qb < 2; ++qb)
#pragma unroll
      for (int r = 0; r < 4; ++r) lsum[qb][r] += __shfl_xor(lsum[qb][r], sh, 64);

#pragma unroll
  for (int qb = 0; qb < 2; ++qb)
#pragma unroll
    for (int r = 0; r < 4; ++r) {
      const float inv = 1.0f / lsum[qb][r];
      const int s = q0 + wave * 32 + qb * 16 + lq * 4 + r;
#pragma unroll
      for (int j = 0; j < 4; ++j) {
        const int col = h * DKn + j * 16 + l15;
        ctxb[((size_t)b * Sn + s) * Dn + col] = (__bf16)(ctx[qb][j][r] * inv);
      }
    }
}

// ---------------------------------------------------------------------------
extern "C" void kernel_launch(void* const* d_in, const int* in_sizes, int n_in,
                              void* d_out, int out_size, void* d_ws, size_t ws_size,
                              hipStream_t stream) {
  const float* q = (const float*)d_in[0];
  const float* k = (const float*)d_in[1];
  const float* v = (const float*)d_in[2];
  const unsigned char* mask = (const unsigned char*)d_in[3];
  const float* Wq = (const float*)d_in[4];
  const float* bq = (const float*)d_in[5];
  const float* Wk = (const float*)d_in[6];
  const float* bk = (const float*)d_in[7];
  const float* Wv = (const float*)d_in[8];
  const float* bv = (const float*)d_in[9];
  const float* Wo = (const float*)d_in[10];
  const float* bo = (const float*)d_in[11];
  float* out = (float*)d_out;

  char* base = (char*)d_ws;
  const size_t XB = (size_t)Mn * Dn * 2;  // 12.58 MB bf16
  const size_t WT = (size_t)Dn * Dn * 2;  // 1.18 MB
  __bf16* qb = (__bf16*)(base);
  __bf16* kb = (__bf16*)(base + XB);
  __bf16* vb = (__bf16*)(base + 2 * XB);
  __bf16* Wt = (__bf16*)(base + 3 * XB);
  __bf16* qh = (__bf16*)(base + 3 * XB + 4 * WT);
  __bf16* kh = (__bf16*)(base + 4 * XB + 4 * WT);
  __bf16* vht = (__bf16*)(base + 5 * XB + 4 * WT);
  int* cidx = (int*)(base + 6 * XB + 4 * WT);
  int* nbp = cidx + Bn * Sn;
  __bf16* ctxb = kb;  // alias: kb dead after qkv gemm

  prep_kernel<<<148, 256, 0, stream>>>(mask, Wq, Wk, Wv, Wo, Wt, cidx, nbp);
  convert_kernel<<<dim3(4096, 1, 3), 256, 0, stream>>>(q, k, v, cidx, nbp, qb, kb, vb);
  qkv_gemm_mfma_kernel<<<dim3(Mn / 128, Dn / 128, 3), 256, 0, stream>>>(
      qb, kb, vb, Wt, nbp, bq, bk, bv, qh, kh, vht);
  attn_mfma_kernel<<<768, 256, 0, stream>>>(qh, kh, vht, nbp, ctxb);
  out_gemm_mfma_kernel<<<dim3(Mn / 128, Dn / 128), 256, 0, stream>>>(ctxb, Wt + 3 * (size_t)Dn * Dn,
                                                                     bo, out);
}

// Round 13
// 113.576 us; speedup vs baseline: 1.0573x; 1.0573x over previous
//
#include <hip/hip_runtime.h>

#define Bn 4
#define Sn 2048
#define Dn 768
#define Hn 12
#define DKn 64
#define Mn (Bn * Sn)

typedef __bf16 bf16x8 __attribute__((ext_vector_type(8)));
typedef float f32x4 __attribute__((ext_vector_type(4)));

static __device__ __forceinline__ float4 ld4(const float* p) { return *(const float4*)p; }

static __device__ __forceinline__ f32x4 mfma16(bf16x8 a, bf16x8 b, f32x4 c) {
  return __builtin_amdgcn_mfma_f32_16x16x32_bf16(a, b, c, 0, 0, 0);
}

// v_cvt_pk_bf16_f32: pack (lo,hi) f32 -> 2 bf16 in one u32 (lo in low half)
static __device__ __forceinline__ unsigned int cvtpk(float lo, float hi) {
  unsigned int r;
  asm("v_cvt_pk_bf16_f32 %0, %1, %2" : "=v"(r) : "v"(lo), "v"(hi));
  return r;
}

// global -> LDS direct copy, 16B per lane. LDS dest = wave-uniform base + lane*16.
static __device__ __forceinline__ void glds16(const void* g, void* l) {
  __builtin_amdgcn_global_load_lds(
      (const __attribute__((address_space(1))) unsigned int*)(uintptr_t)g,
      (__attribute__((address_space(3))) unsigned int*)(unsigned int)(uintptr_t)l, 16, 0, 0);
}

// Swizzled 16B fragment read from a [rows][64 bf16] tile (128B row stride).
// Content at swizzled chunk x of row r = original chunk x ^ (r&7).
static __device__ __forceinline__ bf16x8 ldsfrag(const __bf16* base, int row, int kbyte) {
  const char* p = (const char*)base + row * 128 + (kbyte ^ ((row & 7) << 4));
  return *(const bf16x8*)p;
}

static __device__ __forceinline__ bf16x8 cvt8(float4 a, float4 b) {
  bf16x8 o;
  o[0] = (__bf16)a.x; o[1] = (__bf16)a.y; o[2] = (__bf16)a.z; o[3] = (__bf16)a.w;
  o[4] = (__bf16)b.x; o[5] = (__bf16)b.y; o[6] = (__bf16)b.z; o[7] = (__bf16)b.w;
  return o;
}

// ---------------------------------------------------------------------------
// prep kernel (launch 1), grid (148), block 256:
//  blocks 0..143 -> W transpose, 128x128 f32 tile each (4 x 64x64 subtiles)
//  blocks 144..147 -> per-batch mask compaction index
// ---------------------------------------------------------------------------
__global__ __launch_bounds__(256) void prep_kernel(
    const unsigned char* __restrict__ mask,
    const float* __restrict__ Wq, const float* __restrict__ Wk,
    const float* __restrict__ Wv, const float* __restrict__ Wo,
    __bf16* __restrict__ Wt, int* __restrict__ cidx, int* __restrict__ nbp) {
  const int t = threadIdx.x;
  const int bid = blockIdx.x;

  if (bid < 144) {
    __shared__ __bf16 T[64][72];
    const int zi = bid / 36;
    const int rem = bid % 36;
    const int bx = rem % 6, by = rem / 6;
    const float* W = zi == 0 ? Wq : zi == 1 ? Wk : zi == 2 ? Wv : Wo;
    __bf16* out = Wt + (size_t)zi * Dn * Dn;
    const int k0 = bx * 128, n0 = by * 128;
#pragma unroll
    for (int sk = 0; sk < 2; ++sk)
#pragma unroll
      for (int sn = 0; sn < 2; ++sn) {
        const int kk0 = k0 + sk * 64, nn0 = n0 + sn * 64;
        __syncthreads();
#pragma unroll
        for (int i = 0; i < 4; ++i) {
          int flat = t + i * 256;
          int row = flat >> 4;
          int c4 = (flat & 15) * 4;
          float4 vv = ld4(&W[(size_t)(kk0 + row) * Dn + nn0 + c4]);
          T[c4 + 0][row] = (__bf16)vv.x;
          T[c4 + 1][row] = (__bf16)vv.y;
          T[c4 + 2][row] = (__bf16)vv.z;
          T[c4 + 3][row] = (__bf16)vv.w;
        }
        __syncthreads();
#pragma unroll
        for (int i = 0; i < 2; ++i) {
          int flat = t + i * 256;
          int row = flat >> 3;
          int c8 = (flat & 7) * 8;
          *(bf16x8*)&out[(size_t)(nn0 + row) * Dn + kk0 + c8] = *(bf16x8*)&T[row][c8];
        }
      }
    return;
  }

  // mask index build, one block per batch
  __shared__ int dcnt;
  __shared__ int cnts[256];
  __shared__ int offs[256];
  const int b = bid - 144;
  if (t == 0) dcnt = 0;
  __syncthreads();
  int c = 0;
#pragma unroll
  for (int i = 0; i < 32; ++i) c += (mask[t * 32 + i] != 0) ? 1 : 0;
  atomicAdd(&dcnt, c);
  __syncthreads();
  const int mflag = dcnt > 2457;  // >30% of first 8192 bytes nonzero => byte-bool
  const unsigned char* m8 = mask + (size_t)b * Sn;
  const int* m32 = (const int*)mask + (size_t)b * Sn;
  bool um[8];
  int lc = 0;
#pragma unroll
  for (int i = 0; i < 8; ++i) {
    const int s = t * 8 + i;
    const bool masked = mflag ? (m8[s] != 0) : (m32[s] != 0);
    um[i] = !masked;
    lc += um[i] ? 1 : 0;
  }
  cnts[t] = lc;
  __syncthreads();
  if (t == 0) {
    int acc = 0;
    for (int i = 0; i < 256; ++i) {
      offs[i] = acc;
      acc += cnts[i];
    }
    nbp[b] = acc;
  }
  __syncthreads();
  int o = offs[t];
  int* out = cidx + (size_t)b * Sn;
#pragma unroll
  for (int i = 0; i < 8; ++i)
    if (um[i]) out[o++] = t * 8 + i;
}

// ---------------------------------------------------------------------------
// convert kernel (launch 2), grid (4096, 1, 3), block 256:
//  z=0: q f32->bf16 (blocks 0..3071, 2048 elems each)
//  z=1: k gather-compact-convert (2 rows/block, threads 0..191)
//  z=2: v gather-compact-convert
// ---------------------------------------------------------------------------
__global__ __launch_bounds__(256) void convert_kernel(
    const float* __restrict__ q, const float* __restrict__ k, const float* __restrict__ v,
    const int* __restrict__ cidx, const int* __restrict__ nbp,
    __bf16* __restrict__ qb, __bf16* __restrict__ kb, __bf16* __restrict__ vb) {
  const int t = threadIdx.x;
  const int z = blockIdx.z;
  const int bid = blockIdx.x;

  if (z == 0) {
    if (bid >= 3072) return;
    size_t i = ((size_t)bid * 256 + t) * 8;
    *(bf16x8*)(qb + i) = cvt8(ld4(q + i), ld4(q + i + 4));
    return;
  }
  if (t >= 192) return;
  const float* src = z == 1 ? k : v;
  __bf16* dst = z == 1 ? kb : vb;
  const int b = bid >> 10;
  const int i = ((bid & 1023) << 1) + (t / 96);
  const int c8 = (t % 96) * 8;
  const int nb = nbp[b];
  __bf16* orow = dst + ((size_t)b * Sn + i) * Dn + c8;
  if (i < nb) {
    const int s = cidx[b * Sn + i];
    const float* irow = src + ((size_t)b * Sn + s) * Dn + c8;
    *(bf16x8*)orow = cvt8(ld4(irow), ld4(irow + 4));
  } else {
    bf16x8 zz = {};
    *(bf16x8*)orow = zz;
  }
}

// ---------------------------------------------------------------------------
// MFMA GEMM core (round-5 proven): both operands via glds16. 128x128, BK=64.
// MODE 0: bf16 head-split [b][h][s][dk].  MODE 1: f32 [m][768].
// MODE 2: bf16 head-split transposed [b][h][dk][s'] with the per-64-tile key
// permutation pi(s) = (s&~63)|((s&15)<<2)|((s>>4)&3) matching attn's packed
// P-write layout (P cols and V^T rows permuted identically => PV invariant).
template <int MODE>
static __device__ __forceinline__ void gemm_mfma_core(__bf16* __restrict__ As,
                                                      __bf16* __restrict__ Bs,
                                                      const __bf16* __restrict__ X,
                                                      const __bf16* __restrict__ Bt,
                                                      const float* __restrict__ bias,
                                                      void* __restrict__ Y) {
  const int tid = threadIdx.x;
  const int lane = tid & 63;
  const int wave = __builtin_amdgcn_readfirstlane(tid >> 6);
  const int l15 = lane & 15, lq = lane >> 4;
  const int m0 = blockIdx.x * 128, n0 = blockIdx.y * 128;
  const int wr = wave >> 1, wc = wave & 1;

  f32x4 acc[4][4];
#pragma unroll
  for (int i = 0; i < 4; ++i)
#pragma unroll
    for (int j = 0; j < 4; ++j) acc[i][j] = (f32x4){0.f, 0.f, 0.f, 0.f};

  for (int kt = 0; kt < Dn / 64; ++kt) {
    __syncthreads();
#pragma unroll
    for (int i = 0; i < 4; ++i) {
      int r0 = (i * 4 + wave) * 8;
      int row = r0 + (lane >> 3);
      int chunk = (lane & 7) ^ (row & 7);
      glds16(X + (size_t)(m0 + row) * Dn + kt * 64 + chunk * 8, As + r0 * 64);
      glds16(Bt + (size_t)(n0 + row) * Dn + kt * 64 + chunk * 8, Bs + r0 * 64);
    }
    __syncthreads();
#pragma unroll
    for (int kk = 0; kk < 2; ++kk) {
      bf16x8 a[4], b[4];
#pragma unroll
      for (int i = 0; i < 4; ++i) a[i] = ldsfrag(As, wr * 64 + i * 16 + l15, kk * 64 + lq * 16);
#pragma unroll
      for (int j = 0; j < 4; ++j) b[j] = ldsfrag(Bs, wc * 64 + j * 16 + l15, kk * 64 + lq * 16);
#pragma unroll
      for (int i = 0; i < 4; ++i)
#pragma unroll
        for (int j = 0; j < 4; ++j) acc[i][j] = mfma16(a[i], b[j], acc[i][j]);
    }
  }

#pragma unroll
  for (int i = 0; i < 4; ++i)
#pragma unroll
    for (int j = 0; j < 4; ++j) {
      const int gcol = n0 + wc * 64 + j * 16 + l15;
      const float bv = bias[gcol];
#pragma unroll
      for (int r = 0; r < 4; ++r) {
        const int grow = m0 + wr * 64 + i * 16 + lq * 4 + r;
        const float val = acc[i][j][r] + bv;
        if (MODE == 0) {
          const int b = grow >> 11, s = grow & (Sn - 1);
          const int h = gcol >> 6, dk = gcol & 63;
          ((__bf16*)Y)[(((size_t)b * Hn + h) * Sn + s) * DKn + dk] = (__bf16)val;
        } else if (MODE == 2) {
          const int b = grow >> 11, s = grow & (Sn - 1);
          const int h = gcol >> 6, dk = gcol & 63;
          const int sp = (s & ~63) | ((s & 15) << 2) | ((s >> 4) & 3);
          ((__bf16*)Y)[(((size_t)b * Hn + h) * DKn + dk) * Sn + sp] = (__bf16)val;
        } else {
          ((float*)Y)[(size_t)grow * Dn + gcol] = val;
        }
      }
    }
}

__global__ __launch_bounds__(256, 4) void qkv_gemm_mfma_kernel(
    const __bf16* __restrict__ qb, const __bf16* __restrict__ kb, const __bf16* __restrict__ vb,
    const __bf16* __restrict__ Wt, const int* __restrict__ nbp,
    const float* __restrict__ bq, const float* __restrict__ bk, const float* __restrict__ bv,
    __bf16* __restrict__ qh, __bf16* __restrict__ kh, __bf16* __restrict__ vht) {
  __shared__ __bf16 As[128 * 64];
  __shared__ __bf16 Bs[128 * 64];
  const int z = blockIdx.z;
  if (z != 0) {
    // compacted K/V rows: skip tiles fully beyond this batch's live rows
    const int m0 = blockIdx.x * 128;
    const int b = m0 >> 11, ml = m0 & (Sn - 1);
    const int lim = (nbp[b] + 127) & ~127;
    if (ml >= lim) return;
  }
  if (z == 0) {
    gemm_mfma_core<0>(As, Bs, qb, Wt, bq, qh);
  } else if (z == 1) {
    gemm_mfma_core<0>(As, Bs, kb, Wt + (size_t)Dn * Dn, bk, kh);
  } else {
    gemm_mfma_core<2>(As, Bs, vb, Wt + 2 * (size_t)Dn * Dn, bv, vht);
  }
}

__global__ __launch_bounds__(256, 4) void out_gemm_mfma_kernel(const __bf16* __restrict__ ctxb,
                                                               const __bf16* __restrict__ Wot,
                                                               const float* __restrict__ bo,
                                                               float* __restrict__ out) {
  __shared__ __bf16 As[128 * 64];
  __shared__ __bf16 Bs[128 * 64];
  gemm_mfma_core<1>(As, Bs, ctxb, Wot, bo, out);
}

// ---------------------------------------------------------------------------
// Flash attention over COMPACTED keys, fixed-M softmax.
// P-write packed: with the pi key-permutation (V^T rows permuted identically
// by the qkv GEMM), each lane's 4 P-values per (qb,r) are contiguous ->
// 2x cvt_pk + 1x ds_write_b64 (8 writes/wave-tile instead of 32 b16 writes).
// Block = 128 q-rows of one (b,h); 4 waves x 32 rows. K/V double-buffered.
__global__ __launch_bounds__(256, 3) void attn_mfma_kernel(
    const __bf16* __restrict__ qh, const __bf16* __restrict__ kh, const __bf16* __restrict__ vht,
    const int* __restrict__ nbp, __bf16* __restrict__ ctxb) {
  __shared__ __bf16 QPs[128 * 64];    // Q at start, then P (wave-private rows)
  __shared__ __bf16 KVs[4][64 * 64];  // K0 K1 V0 V1
  const int tid = threadIdx.x;
  const int lane = tid & 63;
  const int wave = __builtin_amdgcn_readfirstlane(tid >> 6);
  const int l15 = lane & 15, lq = lane >> 4;
  const int q0 = blockIdx.x * 128;
  const int bh = blockIdx.y;
  const int b = bh / Hn, h = bh % Hn;
  const int nb = nbp[b];
  const int NT = (nb + 63) >> 6;
  const __bf16* Qg = qh + (size_t)bh * Sn * DKn;
  const __bf16* Kg = kh + (size_t)bh * Sn * DKn;
  const __bf16* Vg = vht + (size_t)bh * DKn * Sn;
  const float C1 = 0.18033688011112042f;  // log2(e)/8
  const float C2 = -23.083120654223414f;  // -16*log2(e)

  auto stageKV = [&](int t, int buf) {
#pragma unroll
    for (int i = 0; i < 2; ++i) {
      int r0 = wave * 16 + i * 8;
      int row = r0 + (lane >> 3);
      int chunk = (lane & 7) ^ (row & 7);
      glds16(Kg + (size_t)(t * 64 + row) * DKn + chunk * 8, (__bf16*)KVs[buf] + r0 * 64);
      glds16(Vg + (size_t)row * Sn + t * 64 + chunk * 8, (__bf16*)KVs[2 + buf] + r0 * 64);
    }
  };

  // stage Q rows [wave*32, wave*32+32)
#pragma unroll
  for (int i = 0; i < 4; ++i) {
    int r0 = wave * 32 + i * 8;
    int row = r0 + (lane >> 3);
    int chunk = (lane & 7) ^ (row & 7);
    glds16(Qg + (size_t)(q0 + row) * DKn + chunk * 8, (__bf16*)QPs + r0 * 64);
  }
  stageKV(0, 0);
  __syncthreads();

  bf16x8 aq[2][2];
#pragma unroll
  for (int qb = 0; qb < 2; ++qb)
#pragma unroll
    for (int kk = 0; kk < 2; ++kk)
      aq[qb][kk] = ldsfrag(QPs, wave * 32 + qb * 16 + l15, kk * 64 + lq * 16);

  f32x4 ctx[2][4];
  float lsum[2][4];
#pragma unroll
  for (int qb = 0; qb < 2; ++qb)
#pragma unroll
    for (int j = 0; j < 4; ++j) {
      ctx[qb][j] = (f32x4){0.f, 0.f, 0.f, 0.f};
      lsum[qb][j] = 0.f;
    }

  int cur = 0;
  for (int t = 0; t < NT; ++t) {
    if (t + 1 < NT) stageKV(t + 1, cur ^ 1);

    // QK^T
    f32x4 sc[2][4];
#pragma unroll
    for (int qb = 0; qb < 2; ++qb)
#pragma unroll
      for (int j = 0; j < 4; ++j) sc[qb][j] = (f32x4){0.f, 0.f, 0.f, 0.f};
#pragma unroll
    for (int kk = 0; kk < 2; ++kk)
#pragma unroll
      for (int j = 0; j < 4; ++j) {
        bf16x8 bk = ldsfrag(KVs[cur], j * 16 + l15, kk * 64 + lq * 16);
        sc[0][j] = mfma16(aq[0][kk], bk, sc[0][j]);
        sc[1][j] = mfma16(aq[1][kk], bk, sc[1][j]);
      }

    // softmax (fixed M), packed P-write: row = wave*32+qb*16+lq*4+r,
    // byte col = (l15*8) ^ ((row&7)<<4); cols l15*4..+3 hold keys 16j+l15.
    const bool lastt = (t == NT - 1);
    const int limit = nb - t * 64;
    bool live[4];
#pragma unroll
    for (int j = 0; j < 4; ++j) live[j] = !lastt || ((j * 16 + l15) < limit);
#pragma unroll
    for (int qb = 0; qb < 2; ++qb)
#pragma unroll
      for (int r = 0; r < 4; ++r) {
        float p[4];
#pragma unroll
        for (int j = 0; j < 4; ++j) {
          float pv = __builtin_amdgcn_exp2f(fmaf(sc[qb][j][r], C1, C2));
          p[j] = live[j] ? pv : 0.f;
          lsum[qb][r] += p[j];
        }
        uint2 w;
        w.x = cvtpk(p[0], p[1]);
        w.y = cvtpk(p[2], p[3]);
        const int row = wave * 32 + qb * 16 + lq * 4 + r;
        char* dst = (char*)QPs + row * 128 + ((l15 * 8) ^ ((row & 7) << 4));
        *(uint2*)dst = w;
      }

    // PV
    bf16x8 pa[2][2];
#pragma unroll
    for (int qb = 0; qb < 2; ++qb)
#pragma unroll
      for (int kk = 0; kk < 2; ++kk)
        pa[qb][kk] = ldsfrag(QPs, wave * 32 + qb * 16 + l15, kk * 64 + lq * 16);
#pragma unroll
    for (int kk = 0; kk < 2; ++kk)
#pragma unroll
      for (int j = 0; j < 4; ++j) {
        bf16x8 bv = ldsfrag(KVs[2 + cur], j * 16 + l15, kk * 64 + lq * 16);
        ctx[0][j] = mfma16(pa[0][kk], bv, ctx[0][j]);
        ctx[1][j] = mfma16(pa[1][kk], bv, ctx[1][j]);
      }

    __syncthreads();
    cur ^= 1;
  }

  // one reduction tree for l over the 16 col-lanes
#pragma unroll
  for (int sh = 1; sh <= 8; sh <<= 1)
#pragma unroll
    for (int qb = 0; qb < 2; ++qb)
#pragma unroll
      for (int r = 0; r < 4; ++r) lsum[qb][r] += __shfl_xor(lsum[qb][r], sh, 64);

#pragma unroll
  for (int qb = 0; qb < 2; ++qb)
#pragma unroll
    for (int r = 0; r < 4; ++r) {
      const float inv = 1.0f / lsum[qb][r];
      const int s = q0 + wave * 32 + qb * 16 + lq * 4 + r;
#pragma unroll
      for (int j = 0; j < 4; ++j) {
        const int col = h * DKn + j * 16 + l15;
        ctxb[((size_t)b * Sn + s) * Dn + col] = (__bf16)(ctx[qb][j][r] * inv);
      }
    }
}

// ---------------------------------------------------------------------------
extern "C" void kernel_launch(void* const* d_in, const int* in_sizes, int n_in,
                              void* d_out, int out_size, void* d_ws, size_t ws_size,
                              hipStream_t stream) {
  const float* q = (const float*)d_in[0];
  const float* k = (const float*)d_in[1];
  const float* v = (const float*)d_in[2];
  const unsigned char* mask = (const unsigned char*)d_in[3];
  const float* Wq = (const float*)d_in[4];
  const float* bq = (const float*)d_in[5];
  const float* Wk = (const float*)d_in[6];
  const float* bk = (const float*)d_in[7];
  const float* Wv = (const float*)d_in[8];
  const float* bv = (const float*)d_in[9];
  const float* Wo = (const float*)d_in[10];
  const float* bo = (const float*)d_in[11];
  float* out = (float*)d_out;

  char* base = (char*)d_ws;
  const size_t XB = (size_t)Mn * Dn * 2;  // 12.58 MB bf16
  const size_t WT = (size_t)Dn * Dn * 2;  // 1.18 MB
  __bf16* qb = (__bf16*)(base);
  __bf16* kb = (__bf16*)(base + XB);
  __bf16* vb = (__bf16*)(base + 2 * XB);
  __bf16* Wt = (__bf16*)(base + 3 * XB);
  __bf16* qh = (__bf16*)(base + 3 * XB + 4 * WT);
  __bf16* kh = (__bf16*)(base + 4 * XB + 4 * WT);
  __bf16* vht = (__bf16*)(base + 5 * XB + 4 * WT);
  int* cidx = (int*)(base + 6 * XB + 4 * WT);
  int* nbp = cidx + Bn * Sn;
  __bf16* ctxb = kb;  // alias: kb dead after qkv gemm

  prep_kernel<<<148, 256, 0, stream>>>(mask, Wq, Wk, Wv, Wo, Wt, cidx, nbp);
  convert_kernel<<<dim3(4096, 1, 3), 256, 0, stream>>>(q, k, v, cidx, nbp, qb, kb, vb);
  qkv_gemm_mfma_kernel<<<dim3(Mn / 128, Dn / 128, 3), 256, 0, stream>>>(
      qb, kb, vb, Wt, nbp, bq, bk, bv, qh, kh, vht);
  attn_mfma_kernel<<<dim3(Sn / 128, Bn * Hn), 256, 0, stream>>>(qh, kh, vht, nbp, ctxb);
  out_gemm_mfma_kernel<<<dim3(Mn / 128, Dn / 128), 256, 0, stream>>>(ctxb, Wt + 3 * (size_t)Dn * Dn,
                                                                     bo, out);
}